// Round 13
// baseline (52.033 us; speedup 1.0000x reference)
//
#include <hip/hip_runtime.h>
#include <hip/hip_bf16.h>

// SmoothLDDTLoss: b=2, n=4096
// inputs: pred_coords f32[2,4096,3], true_coords f32[2,4096,3],
//         is_dna i32[2,4096], is_rna i32[2,4096], coords_mask i32[2,4096]
// output: scalar f32 = 1 - mean_b(lddt_b)
//
// sigma(.5-d)+sigma(1-d)+sigma(2-d)+sigma(4-d) = t*Q'(t)/Q(t), t=e^{-d} (exact).
// Coords pre-scaled by log2(e) so t = exp2(-|dt_s-dp_s|) is a raw v_exp_f32.
//
// Structure: LDS-broadcast N-body tile (r11) + upper triangle (r12) + COMPACT
// grid (r13). r12 lesson: triangle with a dispatched-but-early-exit grid left
// only 544 active blocks = 2.1/CU -> 1 wave/SIMD -> latency-bound (VALUBusy
// 61% -> 30%). Fix: 64-wide j-chunks double the active tile count to 1088
// uniform blocks (4.25/CU), and the grid enumerates ONLY active tiles via the
// closed form C(bi) = 66bi - 2bi^2 (tiny scalar loop), so every resident
// block does full work. Strict j>i excludes the diagonal; the 2x of symmetric
// pairs cancels in s/c.

#define NRES 4096
#define NBATCH 2
#define TJ 64
#define NACT 544                    // per-batch active tiles: sum(64-4bi)
#define NBLOCKS (NACT * NBATCH)

// scaled cutoffs: 15*log2(e), 30*log2(e)
#define CUT15 21.6404256133f
#define CUT30 43.2808512267f

// Q coefficients: elementary symmetric polys of {e^0.5, e^1, e^2, e^4}
#define S1 66.35420923f
#define S2 678.60880385f
#define S3 2039.58217570f
#define S4 1808.04241445f
// Q'(t)/4 coefficients
#define QP1 16.58855231f
#define QP2 339.30440193f
#define QP3 1529.68663177f
#define QP4 1808.04241445f

#define LOG2E 1.44269504089f

__global__ void pack_kernel(const float* __restrict__ pred,
                            const float* __restrict__ truec,
                            const int* __restrict__ dna,
                            const int* __restrict__ rna,
                            const int* __restrict__ cm,
                            float4* __restrict__ tp,
                            float4* __restrict__ pp)
{
    int idx = blockIdx.x * 256 + threadIdx.x;
    if (idx >= NRES * NBATCH) return;
    float nuc = ((dna[idx] | rna[idx]) != 0) ? 1.0f : 0.0f;
    float cmf = (cm[idx] != 0) ? 1.0f : 0.0f;
    tp[idx] = make_float4(truec[3*idx+0]*LOG2E, truec[3*idx+1]*LOG2E, truec[3*idx+2]*LOG2E, nuc);
    pp[idx] = make_float4(pred[3*idx+0]*LOG2E,  pred[3*idx+1]*LOG2E,  pred[3*idx+2]*LOG2E,  cmf);
}

// DIAG=0: interior tile (all j>i guaranteed); DIAG=1: strict j>i predicate
#define K_LOOP(DIAG)                                                        \
    _Pragma("unroll 4")                                                     \
    for (int k = 0; k < TJ; ++k) {                                          \
        const float4 tj = stj[k];                                           \
        const float4 pj = spj[k];                                           \
        float dx = tix - tj.x, dy = tiy - tj.y, dz = tiz - tj.z;            \
        float dt = __builtin_amdgcn_sqrtf(dx*dx + dy*dy + dz*dz);           \
        float ex = pix - pj.x, ey = piy - pj.y, ez = piz - pj.z;            \
        float dp = __builtin_amdgcn_sqrtf(ex*ex + ey*ey + ez*ez);           \
        float cutoff = __builtin_fmaf(tj.w, cHiLo, cLo);                    \
        float mf = (dt < cutoff) ? pj.w : 0.0f;                             \
        if (DIAG) mf = (j0 + k > i) ? mf : 0.0f;                            \
        float t = __builtin_amdgcn_exp2f(-fabsf(dt - dp));                  \
        float Q  = 1.0f + t*(S1 + t*(S2 + t*(S3 + t*S4)));                  \
        float Qp = QP1 + t*(QP2 + t*(QP3 + t*QP4));                         \
        float rq = __builtin_amdgcn_rcpf(Q);                                \
        s += mf * ((t * Qp) * rq);                                          \
        c += mf;                                                            \
    }

__launch_bounds__(256, 6)
__global__ void lddt_main(const float4* __restrict__ tp,
                          const float4* __restrict__ pp,
                          float* __restrict__ acc,          // [0..1] sums, [2..3] counts
                          unsigned int* __restrict__ done,
                          float* __restrict__ out)
{
    const int b   = blockIdx.y;
    const int m   = blockIdx.x;          // compact active-tile index in [0, NACT)
    const int tid = threadIdx.x;

    // decode m -> (bi, cj): active cj in [4bi, 64), cumulative C(bi)=66bi-2bi^2
    int bi = 0, C = 0;
    while (C + (TJ - 4 * bi) <= m) { C += TJ - 4 * bi; ++bi; }
    const int cj = 4 * bi + (m - C);

    const int base = b * NRES;
    const int j0   = cj * TJ;
    const int i    = bi * 256 + tid;

    __shared__ float4 stj[TJ];
    __shared__ float4 spj[TJ];
    if (tid < TJ)                stj[tid]      = tp[base + j0 + tid];
    else if (tid < 2 * TJ)       spj[tid - TJ] = pp[base + j0 + (tid - TJ)];

    const float4 ti4 = tp[base + i];
    const float4 pi4 = pp[base + i];
    const float tix = ti4.x, tiy = ti4.y, tiz = ti4.z;
    const float pix = pi4.x, piy = pi4.y, piz = pi4.z;
    const bool  cmi  = (pi4.w != 0.0f);
    const bool  nuci = (ti4.w != 0.0f);
    const float cHi = cmi ? (nuci ? CUT30 : CUT15) : -1.0f;
    const float cLo = cmi ? CUT15 : -1.0f;
    const float cHiLo = cHi - cLo;       // cutoff = fma(nucj, cHiLo, cLo)

    __syncthreads();

    float s = 0.0f, c = 0.0f;

    if (cj < 4 * bi + 4) { K_LOOP(1) }   // diagonal-straddling tile
    else                 { K_LOOP(0) }   // interior tile (j > i always)

    // wave (64-lane) reduction
    #pragma unroll
    for (int off = 32; off > 0; off >>= 1) {
        s += __shfl_down(s, off, 64);
        c += __shfl_down(c, off, 64);
    }

    __shared__ float red_s[4];
    __shared__ float red_c[4];
    const int wid  = tid >> 6;
    const int lane = tid & 63;
    if (lane == 0) { red_s[wid] = s; red_c[wid] = c; }
    __syncthreads();

    if (tid == 0) {
        float ts = red_s[0] + red_s[1] + red_s[2] + red_s[3];
        float tc = red_c[0] + red_c[1] + red_c[2] + red_c[3];
        atomicAdd(&acc[b], ts);
        atomicAdd(&acc[NBATCH + b], tc);
        __threadfence();
        unsigned int old = atomicAdd(done, 1u);
        if (old == NBLOCKS - 1u) {
            float a0 = __hip_atomic_load(&acc[0], __ATOMIC_ACQUIRE, __HIP_MEMORY_SCOPE_AGENT);
            float a1 = __hip_atomic_load(&acc[1], __ATOMIC_ACQUIRE, __HIP_MEMORY_SCOPE_AGENT);
            float c0 = __hip_atomic_load(&acc[2], __ATOMIC_ACQUIRE, __HIP_MEMORY_SCOPE_AGENT);
            float c1 = __hip_atomic_load(&acc[3], __ATOMIC_ACQUIRE, __HIP_MEMORY_SCOPE_AGENT);
            float l0 = a0 / fmaxf(c0, 0.5f);
            float l1 = a1 / fmaxf(c1, 0.5f);
            out[0] = 1.0f - 0.5f * (l0 + l1);
        }
    }
}

extern "C" void kernel_launch(void* const* d_in, const int* in_sizes, int n_in,
                              void* d_out, int out_size, void* d_ws, size_t ws_size,
                              hipStream_t stream) {
    const float* pred  = (const float*)d_in[0];
    const float* truec = (const float*)d_in[1];
    const int*   dna   = (const int*)d_in[2];
    const int*   rna   = (const int*)d_in[3];
    const int*   cmask = (const int*)d_in[4];
    float* out = (float*)d_out;

    char* ws = (char*)d_ws;
    float*        acc  = (float*)ws;              // 4 floats
    unsigned int* done = (unsigned int*)(ws + 64);
    float4* tp = (float4*)(ws + 1024);            // 2*4096*16 B
    float4* pp = (float4*)(ws + 1024 + NBATCH*NRES*16);

    (void)hipMemsetAsync(ws, 0, 128, stream);     // acc + done

    pack_kernel<<<(NRES*NBATCH + 255)/256, 256, 0, stream>>>(pred, truec, dna, rna, cmask, tp, pp);

    dim3 grid(NACT, NBATCH);
    lddt_main<<<grid, 256, 0, stream>>>(tp, pp, acc, done, out);
}

// Round 14
// 48.067 us; speedup vs baseline: 1.0825x; 1.0825x over previous
//
#include <hip/hip_runtime.h>
#include <hip/hip_bf16.h>

// SmoothLDDTLoss: b=2, n=4096
// inputs: pred_coords f32[2,4096,3], true_coords f32[2,4096,3],
//         is_dna i32[2,4096], is_rna i32[2,4096], coords_mask i32[2,4096]
// output: scalar f32 = 1 - mean_b(lddt_b)
//
// sigma(.5-d)+sigma(1-d)+sigma(2-d)+sigma(4-d) = t*Q'(t)/Q(t), t=e^{-d} (exact).
// Coords pre-scaled by log2(e) so t = exp2(-|dt_s-dp_s|) is a raw v_exp_f32.
//
// r13 lesson (r4/r6/r9/r10/r11/r13 all pinned at 41-48us regardless of work):
// wall time fits dur ~ NWG * ~35ns + T_block across ALL rounds -> we are
// workgroup-dispatch/ramp-rate bound, not pipe-bound. Fix: PERSISTENT blocks.
// 256 WGs x 1024 threads dispatched once; tiles (1024i x 32j, upper triangle,
// 640 total over 2 batches) are pulled from an atomic work counter (dynamic
// load balance vs CP ramp). Tile interior = r11's LDS-broadcast (conflict-free
// uniform-address reads). Strict j>i on the 4 straddle chunks per i-block;
// symmetric 2x cancels in s/c; diagonal excluded by strict inequality.
// (256,?) VGPR note: r7 showed a 64-VGPR cap spills this body; (1024,4) caps
// at 128 VGPR which is safe (~40 live).

#define NRES 4096
#define NBATCH 2
#define TIB 1024                 // i-rows per tile = block threads
#define TJ 32                    // j-cols per tile
#define NTILE_B 320              // active tiles per batch: sum_{bi<4}(128-32bi)
#define NTILES (NTILE_B * NBATCH)
#define NPBLK 256                // persistent blocks

// scaled cutoffs: 15*log2(e), 30*log2(e)
#define CUT15 21.6404256133f
#define CUT30 43.2808512267f

// Q coefficients: elementary symmetric polys of {e^0.5, e^1, e^2, e^4}
#define S1 66.35420923f
#define S2 678.60880385f
#define S3 2039.58217570f
#define S4 1808.04241445f
// Q'(t)/4 coefficients
#define QP1 16.58855231f
#define QP2 339.30440193f
#define QP3 1529.68663177f
#define QP4 1808.04241445f

#define LOG2E 1.44269504089f

__global__ void pack_kernel(const float* __restrict__ pred,
                            const float* __restrict__ truec,
                            const int* __restrict__ dna,
                            const int* __restrict__ rna,
                            const int* __restrict__ cm,
                            float4* __restrict__ tp,
                            float4* __restrict__ pp)
{
    int idx = blockIdx.x * 256 + threadIdx.x;
    if (idx >= NRES * NBATCH) return;
    float nuc = ((dna[idx] | rna[idx]) != 0) ? 1.0f : 0.0f;
    float cmf = (cm[idx] != 0) ? 1.0f : 0.0f;
    tp[idx] = make_float4(truec[3*idx+0]*LOG2E, truec[3*idx+1]*LOG2E, truec[3*idx+2]*LOG2E, nuc);
    pp[idx] = make_float4(pred[3*idx+0]*LOG2E,  pred[3*idx+1]*LOG2E,  pred[3*idx+2]*LOG2E,  cmf);
}

// DIAG=0: interior tile (all j>i guaranteed); DIAG=1: strict j>i predicate
#define K_LOOP(DIAG)                                                        \
    _Pragma("unroll 4")                                                     \
    for (int k = 0; k < TJ; ++k) {                                          \
        const float4 tj = stj[k];                                           \
        const float4 pj = spj[k];                                           \
        float dx = tix - tj.x, dy = tiy - tj.y, dz = tiz - tj.z;            \
        float dt = __builtin_amdgcn_sqrtf(dx*dx + dy*dy + dz*dz);           \
        float ex = pix - pj.x, ey = piy - pj.y, ez = piz - pj.z;            \
        float dp = __builtin_amdgcn_sqrtf(ex*ex + ey*ey + ez*ez);           \
        float cutoff = __builtin_fmaf(tj.w, cHiLo, cLo);                    \
        float mf = (dt < cutoff) ? pj.w : 0.0f;                             \
        if (DIAG) mf = (j0 + k > i) ? mf : 0.0f;                            \
        float t = __builtin_amdgcn_exp2f(-fabsf(dt - dp));                  \
        float Q  = 1.0f + t*(S1 + t*(S2 + t*(S3 + t*S4)));                  \
        float Qp = QP1 + t*(QP2 + t*(QP3 + t*QP4));                         \
        float rq = __builtin_amdgcn_rcpf(Q);                                \
        s += mf * ((t * Qp) * rq);                                          \
        cc += mf;                                                           \
    }

__launch_bounds__(1024, 4)
__global__ void lddt_main(const float4* __restrict__ tp,
                          const float4* __restrict__ pp,
                          float* __restrict__ acc,          // [0..1] sums, [2..3] counts
                          unsigned int* __restrict__ work,  // tile counter
                          unsigned int* __restrict__ done,  // block-completion counter
                          float* __restrict__ out)
{
    const int tid  = threadIdx.x;
    const int wid  = tid >> 6;
    const int lane = tid & 63;

    __shared__ float4 stj[TJ];
    __shared__ float4 spj[TJ];
    __shared__ unsigned int sm;

    float s0 = 0.0f, c0 = 0.0f, s1 = 0.0f, c1 = 0.0f;

    for (;;) {
        if (tid == 0) sm = atomicAdd(work, 1u);
        __syncthreads();                 // publish sm; prior tile's readers done
        const unsigned int m = sm;
        if (m >= NTILES) break;

        const int b  = (m >= NTILE_B) ? 1 : 0;
        const int mm = m - b * NTILE_B;
        int bi, cj;
        if      (mm < 128) { bi = 0; cj = mm; }
        else if (mm < 224) { bi = 1; cj = 32 + (mm - 128); }
        else if (mm < 288) { bi = 2; cj = 64 + (mm - 224); }
        else               { bi = 3; cj = 96 + (mm - 288); }

        const int base = b * NRES;
        const int j0   = cj * TJ;

        if (tid < TJ)          stj[tid]      = tp[base + j0 + tid];
        else if (tid < 2 * TJ) spj[tid - TJ] = pp[base + j0 + (tid - TJ)];

        const int i = bi * TIB + tid;
        const float4 ti4 = tp[base + i];
        const float4 pi4 = pp[base + i];
        const float tix = ti4.x, tiy = ti4.y, tiz = ti4.z;
        const float pix = pi4.x, piy = pi4.y, piz = pi4.z;
        const bool  cmi  = (pi4.w != 0.0f);
        const bool  nuci = (ti4.w != 0.0f);
        const float cHi = cmi ? (nuci ? CUT30 : CUT15) : -1.0f;
        const float cLo = cmi ? CUT15 : -1.0f;
        const float cHiLo = cHi - cLo;   // cutoff = fma(nucj, cHiLo, cLo)

        __syncthreads();                 // stage visible

        float s = 0.0f, cc = 0.0f;
        if (cj < 32 * bi + 32) { K_LOOP(1) }   // diagonal-straddling chunk
        else                   { K_LOOP(0) }   // interior chunk (j>i always)

        if (b) { s1 += s; c1 += cc; }
        else   { s0 += s; c0 += cc; }
    }

    // wave (64-lane) reduction of 4 accumulators
    #pragma unroll
    for (int off = 32; off > 0; off >>= 1) {
        s0 += __shfl_down(s0, off, 64);
        c0 += __shfl_down(c0, off, 64);
        s1 += __shfl_down(s1, off, 64);
        c1 += __shfl_down(c1, off, 64);
    }

    __shared__ float red[16][4];
    if (lane == 0) { red[wid][0] = s0; red[wid][1] = c0; red[wid][2] = s1; red[wid][3] = c1; }
    __syncthreads();

    if (tid == 0) {
        float ts0 = 0, tc0 = 0, ts1 = 0, tc1 = 0;
        #pragma unroll
        for (int w = 0; w < 16; ++w) {
            ts0 += red[w][0]; tc0 += red[w][1];
            ts1 += red[w][2]; tc1 += red[w][3];
        }
        atomicAdd(&acc[0], ts0);
        atomicAdd(&acc[2], tc0);
        atomicAdd(&acc[1], ts1);
        atomicAdd(&acc[3], tc1);
        __threadfence();
        unsigned int old = atomicAdd(done, 1u);
        if (old == NPBLK - 1u) {
            float a0 = __hip_atomic_load(&acc[0], __ATOMIC_ACQUIRE, __HIP_MEMORY_SCOPE_AGENT);
            float a1 = __hip_atomic_load(&acc[1], __ATOMIC_ACQUIRE, __HIP_MEMORY_SCOPE_AGENT);
            float cc0 = __hip_atomic_load(&acc[2], __ATOMIC_ACQUIRE, __HIP_MEMORY_SCOPE_AGENT);
            float cc1 = __hip_atomic_load(&acc[3], __ATOMIC_ACQUIRE, __HIP_MEMORY_SCOPE_AGENT);
            float l0 = a0 / fmaxf(cc0, 0.5f);
            float l1 = a1 / fmaxf(cc1, 0.5f);
            out[0] = 1.0f - 0.5f * (l0 + l1);
        }
    }
}

extern "C" void kernel_launch(void* const* d_in, const int* in_sizes, int n_in,
                              void* d_out, int out_size, void* d_ws, size_t ws_size,
                              hipStream_t stream) {
    const float* pred  = (const float*)d_in[0];
    const float* truec = (const float*)d_in[1];
    const int*   dna   = (const int*)d_in[2];
    const int*   rna   = (const int*)d_in[3];
    const int*   cmask = (const int*)d_in[4];
    float* out = (float*)d_out;

    char* ws = (char*)d_ws;
    float*        acc  = (float*)ws;               // 4 floats
    unsigned int* done = (unsigned int*)(ws + 64);
    unsigned int* work = (unsigned int*)(ws + 96);
    float4* tp = (float4*)(ws + 1024);             // 2*4096*16 B
    float4* pp = (float4*)(ws + 1024 + NBATCH*NRES*16);

    (void)hipMemsetAsync(ws, 0, 128, stream);      // acc + done + work

    pack_kernel<<<(NRES*NBATCH + 255)/256, 256, 0, stream>>>(pred, truec, dna, rna, cmask, tp, pp);

    lddt_main<<<NPBLK, 1024, 0, stream>>>(tp, pp, acc, work, done, out);
}